// Round 11
// baseline (108.171 us; speedup 1.0000x reference)
//
#include <hip/hip_runtime.h>
#include <math.h>

// Problem constants (from reference)
#define BB 4
#define HH 512
#define WW 512
#define CC 32      // channels; 32 floats = 8 float4 = 128 B per point
#define HO 256
#define WO 256

#define MAXOCC 64   // shared-col slots incl sentinel 0; real slots 1..63
#define OVFCAP 36   // max shared-col cells (99) - 63

// Fill index grid with zeros (0 == empty). int4-vectorized.
__global__ void fill_zero_kernel(int4* __restrict__ g, int n4) {
    int i = blockIdx.x * blockDim.x + threadIdx.x;
    if (i < n4) g[i] = make_int4(0, 0, 0, 0);
}

// Scatter point index+1 into dense (B,H,W) int grid.
__global__ void scatter_idx_kernel(const int* __restrict__ coors,
                                   int* __restrict__ grid, int n) {
    int i = blockIdx.x * blockDim.x + threadIdx.x;
    if (i >= n) return;
    int b = coors[i * 3 + 0];
    int y = coors[i * 3 + 1];
    int x = coors[i * 3 + 2];
    grid[((size_t)b * HH + y) * WW + x] = i + 1;
}

// Block = 32 ox x 1 oy x 8 cg.
// CENTER path (col 2*ox, 1 output each): per-thread, no LDS/barrier —
//   3 grid ints + 3 clamped feature loads issued at kernel top, so this
//   2-round-trip chain overlaps the shared path's barriers.
// SHARED path (odd cols, 2 outputs each): 99 cells -> ballot compaction,
//   LDS staging with -inf sentinel slot 0, swizzled conflict-free reads.
__global__ void __launch_bounds__(256, 8)
pool_kernel(const float4* __restrict__ feat,   // N x 8 float4
            const int* __restrict__ grid,      // B*H*W
            float4* __restrict__ out) {        // B*HO*WO x 8 float4
    // blockIdx.x: [b(2b) | oy(8b) | ox_tile(3b)]
    int ox_base = (blockIdx.x & 7) * 32;
    int oy      = (blockIdx.x >> 3) & (HO - 1);
    int b       = blockIdx.x >> 11;

    int tid  = threadIdx.x;
    int lane = tid & 63;
    int cg   = tid & 7;         // channel group 0..7
    int p    = tid >> 3;        // local position 0..31

    int iy0 = 2 * oy - 1;
    int gx0 = 2 * ox_base - 1;
    const int* gb = grid + (size_t)b * (HH * WW);

    const float NEG = -INFINITY;

    // ---- CENTER path: issue first, consumed last (overlaps shared path)
    int cx = 2 * (ox_base + p);          // always in [0,510]
    int vc[3];
#pragma unroll
    for (int r = 0; r < 3; ++r) {
        int iy = iy0 + r;
        vc[r] = ((unsigned)iy < (unsigned)HH) ? gb[iy * WW + cx] : 0;
    }
    float4 fc[3];
#pragma unroll
    for (int r = 0; r < 3; ++r) {
        int ridx = vc[r] - 1;
        ridx = ridx < 0 ? 0 : ridx;      // empty -> row 0 (L1 broadcast)
        fc[r] = feat[(size_t)ridx * 8 + cg];
    }

    // ---- SHARED-col path
    __shared__ int    cnt;
    __shared__ int    smap[3 * 33];        // slot; 0 = empty/sentinel
    __shared__ int    srcidx[MAXOCC];
    __shared__ float4 sfeat[MAXOCC * 8];   // swizzled: [s*8 + ((cg+s)&7)]
    __shared__ int    ovf_c[OVFCAP];       // overflow cell id (0..98)
    __shared__ int    ovf_i[OVFCAP];       // overflow point index

    if (tid == 0) cnt = 0;
    if (tid < 8) sfeat[tid] = make_float4(NEG, NEG, NEG, NEG);  // sentinel
    __syncthreads();

    // Pass A: 99 shared cells (3 rows x 33 odd cols), ballot compaction
    {
        int vs = 0;
        if (tid < 99) {
            int r  = tid / 33;
            int c2 = tid - r * 33;
            int iy = iy0 + r;
            int gx = gx0 + 2 * c2;
            if ((unsigned)iy < (unsigned)HH && (unsigned)gx < (unsigned)WW)
                vs = gb[iy * WW + gx];
        }
        unsigned long long mask = __ballot(vs != 0);
        int nz = (int)__popcll(mask);
        int base = 0;
        if (lane == 0 && nz) base = atomicAdd(&cnt, nz);
        base = __shfl(base, 0);
        int s = 1 + base + (int)__popcll(mask & ((1ull << lane) - 1ull));
        if (tid < 99) {
            int m = 0;
            if (vs != 0) {
                if (s < MAXOCC) { srcidx[s] = vs - 1; m = s; }
                else {
                    int o = s - MAXOCC;           // ~never (cnt>63, +7.7σ)
                    ovf_c[o] = tid;
                    ovf_i[o] = vs - 1;
                }
            }
            smap[tid] = m;
        }
    }
    __syncthreads();

    // Pass B: stage shared-col rows (slots 1..min(cnt,63))
    int hi = cnt < (MAXOCC - 1) ? cnt : (MAXOCC - 1);
    for (int s = 1 + (tid >> 3); s <= hi; s += 32)
        sfeat[(s << 3) + ((cg + s) & 7)] = feat[(size_t)srcidx[s] * 8 + cg];
    __syncthreads();

    // Pass C: 6 sentinel-guarded LDS reads + 3 prefetched center rows
    float4 acc = make_float4(NEG, NEG, NEG, NEG);
#pragma unroll
    for (int r = 0; r < 3; ++r) {
        int m0 = smap[r * 33 + p];          // shared col 2*ox-1
        int m2 = smap[r * 33 + p + 1];      // shared col 2*ox+1
        float4 f0 = sfeat[(m0 << 3) + ((cg + m0) & 7)];
        float4 f2 = sfeat[(m2 << 3) + ((cg + m2) & 7)];
        acc.x = fmaxf(acc.x, fmaxf(f0.x, f2.x));
        acc.y = fmaxf(acc.y, fmaxf(f0.y, f2.y));
        acc.z = fmaxf(acc.z, fmaxf(f0.z, f2.z));
        acc.w = fmaxf(acc.w, fmaxf(f0.w, f2.w));
        bool ok = vc[r] != 0;
        acc.x = fmaxf(acc.x, ok ? fc[r].x : NEG);
        acc.y = fmaxf(acc.y, ok ? fc[r].y : NEG);
        acc.z = fmaxf(acc.z, ok ? fc[r].z : NEG);
        acc.w = fmaxf(acc.w, ok ? fc[r].w : NEG);
    }

    // block-uniform overflow fixup (prob ~1e-6)
    if (cnt >= MAXOCC) {
        int novf = cnt - (MAXOCC - 1);
        if (novf > OVFCAP) novf = OVFCAP;
        for (int o = 0; o < novf; ++o) {
            int cell = ovf_c[o];
            int c2 = cell % 33;
            if (c2 == p || c2 == p + 1) {       // outputs sharing this col
                float4 fv = feat[(size_t)ovf_i[o] * 8 + cg];
                acc.x = fmaxf(acc.x, fv.x);
                acc.y = fmaxf(acc.y, fv.y);
                acc.z = fmaxf(acc.z, fv.z);
                acc.w = fmaxf(acc.w, fv.w);
            }
        }
    }

    acc.x = isinf(acc.x) ? 0.0f : acc.x;
    acc.y = isinf(acc.y) ? 0.0f : acc.y;
    acc.z = isinf(acc.z) ? 0.0f : acc.z;
    acc.w = isinf(acc.w) ? 0.0f : acc.w;

    size_t pos = ((size_t)(b * HO + oy) * WO + ox_base + p);
    out[pos * 8 + cg] = acc;
}

extern "C" void kernel_launch(void* const* d_in, const int* in_sizes, int n_in,
                              void* d_out, int out_size, void* d_ws, size_t ws_size,
                              hipStream_t stream) {
    const float* features = (const float*)d_in[0];   // N x 32 fp32
    const int*   coors    = (const int*)d_in[1];     // N x 3 int32
    int n = in_sizes[0] / CC;                        // N = 300000

    int* grid = (int*)d_ws;                          // B*H*W int32 = 4 MiB

    // 1) zero the index grid (0xAA-poisoned every timed call)
    {
        int n4 = (BB * HH * WW) / 4;                 // 262144 int4
        int blk = 256, grd = (n4 + blk - 1) / blk;
        fill_zero_kernel<<<grd, blk, 0, stream>>>((int4*)grid, n4);
    }
    // 2) scatter indices
    {
        int blk = 256, grd = (n + blk - 1) / blk;
        scatter_idx_kernel<<<grd, blk, 0, stream>>>(coors, grid, n);
    }
    // 3) pool: 8192 blocks (32 ox x 1 oy x 8 cg per block), 8 blocks/CU
    {
        int grd = BB * HO * (WO / 32);               // 8192
        pool_kernel<<<grd, 256, 0, stream>>>((const float4*)features, grid,
                                             (float4*)d_out);
    }
}